// Round 6
// baseline (1027.764 us; speedup 1.0000x reference)
//
#include <hip/hip_runtime.h>

// ---------------------------------------------------------------------------
// BiLSTM-CRF forward loss on MI355X (gfx950).
// memset(out=NaN) + prep -> bert GEMM -> layer0 input-proj GEMM (bf16 gates)
//   -> coop LSTM (layer0) -> layer1 input-proj GEMM -> coop LSTM (layer1)
//   -> heads GEMM -> CRF.
// Round 6: gates stored transposed bf16 [dir][s][2048][32] (one u64 load per
// lane per step, half the write traffic); lstm gate prefetch issued AFTER the
// retry loop so retry vmcnt waits only on h staging loads.
// ---------------------------------------------------------------------------

typedef unsigned short u16;
typedef unsigned int u32;
typedef unsigned long long u64;
typedef __attribute__((ext_vector_type(8))) __bf16 bf16x8;
typedef __attribute__((ext_vector_type(4))) float floatx4;

static __device__ __forceinline__ u16 f2bf(float f) {
  u32 u = __float_as_uint(f);
  u += 0x7fffu + ((u >> 16) & 1u);   // round-to-nearest-even
  return (u16)(u >> 16);
}
static __device__ __forceinline__ float bf2f(u32 bits) {
  return __uint_as_float(bits << 16);
}
static __device__ __forceinline__ float sigf(float x) {
  return 1.0f / (1.0f + __expf(-x));
}
static __device__ __forceinline__ float tanh_(float x) {
  return 1.0f - 2.0f / (1.0f + __expf(2.0f * x));
}
static __device__ __forceinline__ floatx4 mfma16(bf16x8 a, bf16x8 b, floatx4 c) {
  return __builtin_amdgcn_mfma_f32_16x16x32_bf16(a, b, c, 0, 0, 0);
}

// ---------------------------------------------------------------------------
// prep: fp32->bf16 conversions + bias sums + zero d_out
// ---------------------------------------------------------------------------
__global__ __launch_bounds__(256) void prep_kernel(
    const float* __restrict__ w_ih, const float* __restrict__ w_hh,
    const float* __restrict__ b_ih, const float* __restrict__ b_hh,
    const float* __restrict__ src,  const float* __restrict__ bert,
    const float* __restrict__ hwp,  const float* __restrict__ hbp,
    const float* __restrict__ hwm,  const float* __restrict__ hbm,
    u16* __restrict__ Wsrc, u16* __restrict__ Wbert, u16* __restrict__ Wih1,
    u16* __restrict__ Whh,  u16* __restrict__ SrcBf, u16* __restrict__ BertBf,
    u16* __restrict__ Wheads, float* __restrict__ b0sum, float* __restrict__ b1sum,
    float* __restrict__ hb, float* __restrict__ dout)
{
  const int NA = 4194304;  // w_ih layer0 -> Wsrc (cols 0:256) + Wbert (256:1024)
  const int NB = 4194304;  // w_ih layer1
  const int NC = 4194304;  // w_hh (both layers)
  const int ND = 1048576;  // src
  const int NE = 24576;    // bert
  const int NF = 98304;    // head weights
  const int NG = 8192;     // bias sums
  const int NH = 96;       // head bias
  const int TOTAL = NA + NB + NC + ND + NE + NF + NG + NH + 1;
  for (int i = blockIdx.x * 256 + threadIdx.x; i < TOTAL; i += gridDim.x * 256) {
    int x = i;
    if (x < NA) {
      int c = x & 1023, r = x >> 10;          // r = dir*2048 + row
      float v = w_ih[x];
      if (c < 256) Wsrc[r * 256 + c] = f2bf(v);
      else         Wbert[r * 768 + (c - 256)] = f2bf(v);
      continue;
    }
    x -= NA;
    if (x < NB) { Wih1[x] = f2bf(w_ih[NA + x]); continue; }
    x -= NB;
    if (x < NC) { Whh[x] = f2bf(w_hh[x]); continue; }
    x -= NC;
    if (x < ND) { SrcBf[x] = f2bf(src[x]); continue; }
    x -= ND;
    if (x < NE) { BertBf[x] = f2bf(bert[x]); continue; }
    x -= NE;
    if (x < NF) {
      Wheads[x] = f2bf(x < 32768 ? hwp[x] : hwm[x - 32768]);
      continue;
    }
    x -= NF;
    if (x < NG) {
      float v = b_ih[x] + b_hh[x];
      if (x < 4096) b0sum[x] = v; else b1sum[x - 4096] = v;
      continue;
    }
    x -= NG;
    if (x < NH) { hb[x] = (x < 32) ? hbp[x] : hbm[x - 32]; continue; }
    dout[0] = 0.f;
  }
}

// ---------------------------------------------------------------------------
// bf16 NT GEMM: acc[m][n] = sum_k A[m][k]*B[n][k] (+bias[n]) (+aux[m%32][n])
// 128x128 tile, BK=64, XOR-swizzled LDS.
// mode 0: C fp32 at C[m*ldc+n].
// mode 1: bf16 transposed gates: G[dir][s][nn][b] with dir=n>>11, nn=n&2047,
//         s=m>>5, b=m&31; 4 batches packed per u64 store.
// ---------------------------------------------------------------------------
__global__ __launch_bounds__(256) void gemm_nt(
    const u16* __restrict__ A, int lda,
    const u16* __restrict__ B, int ldb,
    float* __restrict__ C, int ldc,
    int M, int N, int K,
    const float* __restrict__ bias_n,
    const float* __restrict__ auxBN, int auxld,
    int mode)
{
  __shared__ __align__(16) u16 As[128 * 64];
  __shared__ __align__(16) u16 Bs[128 * 64];
  const int m0 = blockIdx.y * 128, n0 = blockIdx.x * 128;
  const int tid = threadIdx.x;
  const int wv = tid >> 6, ln = tid & 63;
  const int wm = wv & 1, wn = wv >> 1;
  const int q = ln >> 4, l15 = ln & 15;
  floatx4 acc[4][4];
#pragma unroll
  for (int a = 0; a < 4; ++a)
#pragma unroll
    for (int b2 = 0; b2 < 4; ++b2) acc[a][b2] = (floatx4){0.f, 0.f, 0.f, 0.f};

  for (int kk = 0; kk < K; kk += 64) {
    __syncthreads();
#pragma unroll
    for (int j = 0; j < 4; ++j) {
      const int idx = j * 256 + tid;   // 1024 16B chunks per operand tile
      const int r = idx >> 3, cc = idx & 7;
      const int slot = cc ^ (r & 7);
      const int ra = min(m0 + r, M - 1);
      *(int4*)&As[r * 64 + slot * 8] = *(const int4*)&A[(long)ra * lda + kk + cc * 8];
      const int rb = min(n0 + r, N - 1);
      *(int4*)&Bs[r * 64 + slot * 8] = *(const int4*)&B[(long)rb * ldb + kk + cc * 8];
    }
    __syncthreads();
#pragma unroll
    for (int ks = 0; ks < 2; ++ks) {
      bf16x8 af[4], bf[4];
#pragma unroll
      for (int im = 0; im < 4; ++im) {
        const int r = wm * 64 + im * 16 + l15;
        const int slot = (ks * 4 + q) ^ (r & 7);
        af[im] = *(const bf16x8*)&As[r * 64 + slot * 8];
      }
#pragma unroll
      for (int jn = 0; jn < 4; ++jn) {
        const int r = wn * 64 + jn * 16 + l15;
        const int slot = (ks * 4 + q) ^ (r & 7);
        bf[jn] = *(const bf16x8*)&Bs[r * 64 + slot * 8];
      }
#pragma unroll
      for (int im = 0; im < 4; ++im)
#pragma unroll
        for (int jn = 0; jn < 4; ++jn)
          acc[im][jn] = mfma16(af[im], bf[jn], acc[im][jn]);
    }
  }
  // epilogue: C/D layout col=lane&15, row=(lane>>4)*4+reg
  if (mode == 0) {
#pragma unroll
    for (int im = 0; im < 4; ++im)
#pragma unroll
      for (int jn = 0; jn < 4; ++jn) {
        const int n = n0 + wn * 64 + jn * 16 + l15;
        if (n < N) {
          const float badd = bias_n ? bias_n[n] : 0.f;
#pragma unroll
          for (int rg = 0; rg < 4; ++rg) {
            const int m = m0 + wm * 64 + im * 16 + q * 4 + rg;
            if (m < M) {
              float v = acc[im][jn][rg] + badd;
              if (auxBN) v += auxBN[(long)(m & 31) * auxld + n];
              C[(long)m * ldc + n] = v;
            }
          }
        }
      }
  } else {
    u16* G = (u16*)C;
#pragma unroll
    for (int im = 0; im < 4; ++im)
#pragma unroll
      for (int jn = 0; jn < 4; ++jn) {
        const int n = n0 + wn * 64 + jn * 16 + l15;
        const int dirsel = n >> 11, nn = n & 2047;
        const int m = m0 + wm * 64 + im * 16 + q * 4;   // rg=0 row
        const int s = m >> 5, b0 = m & 31;              // b0..b0+3 contiguous
        const float badd = bias_n ? bias_n[n] : 0.f;
        u64 pk = 0;
#pragma unroll
        for (int rg = 0; rg < 4; ++rg) {
          float v = acc[im][jn][rg] + badd;
          if (auxBN) v += auxBN[(long)(b0 + rg) * auxld + n];
          pk |= (u64)f2bf(v) << (16 * rg);
        }
        *(u64*)&G[(long)dirsel * 8388608 + ((long)s * 2048 + nn) * 32 + b0] = pk;
      }
  }
}

// ---------------------------------------------------------------------------
// persistent cooperative LSTM recurrence, one layer, both directions.
// 128 blocks x 256 thr: block = (dir, batch-half of 16, 16 hidden units).
// Dataflow sync: out pre-filled with bf16 NaN 0xFFFF; producers store h as
// atomic u64; consumers retry coalesced atomic u64 loads until non-sentinel.
// Gate prefetch (one u64 of 4 bf16) issued AFTER the retry loop so the retry
// vmcnt domain contains only the staging loads.
// ---------------------------------------------------------------------------
__global__ __launch_bounds__(256, 1) void lstm_rec(
    const u16* __restrict__ gates,  // [2][128][2048][32] bf16
    u16* __restrict__ out,          // [128][32][1024] bf16 (fwd | bwd)
    const u16* __restrict__ whh)    // [2][2048][512] bf16 (this layer)
{
  __shared__ __align__(16) u16 h_lds[16 * 512];
  __shared__ float gsc[4][16][17];
  const int bid = blockIdx.x;
  const int dir = bid >> 6;
  const int mh = (bid >> 5) & 1;
  const int u0 = (bid & 31) * 16;
  const int tid = threadIdx.x;
  const int wv = tid >> 6;
  const int ln = tid & 63;
  const int q = ln >> 4, l15 = ln & 15;

  // gate row for this lane's B-frag column n=l15: (n>>2)=gate type, (n&3)=unit
  const int gate_r = (l15 >> 2) * 512 + u0 + wv * 4 + (l15 & 3);

  bf16x8 bfrag[16];
  {
    const u16* wp = whh + ((long)dir * 2048 + gate_r) * 512 + q * 8;
#pragma unroll
    for (int ks = 0; ks < 16; ++ks)
      bfrag[ks] = *(const bf16x8*)(wp + ks * 32);
  }

  float c = 0.f;                       // cell state for (b_glob, j_lane)
  const int b_glob = mh * 16 + l15;    // batch (update phase)

  // lane's gate base: one u64 (4 bf16, batches q*4..q*4+3) per step
  const u16* gbase = gates + (long)dir * 8388608 + (long)gate_r * 32 + mh * 16 + q * 4;

  u64 gcur = *(const u64*)(gbase + (long)(dir ? 127 : 0) * 65536);
  u64 gnext = 0;

  for (int t = 0; t < 128; ++t) {
    const int s = dir ? (127 - t) : t;
    floatx4 acc = (floatx4){0.f, 0.f, 0.f, 0.f};
    u64 v8[8];
    if (t > 0) {
      // stage h(t-1): 16 rows x 512 cols bf16. Coalesced device-scope u64
      // loads; each u64 = one producer wave's atomic store -> check low u16.
      const int sp = dir ? (s + 1) : (s - 1);
      const u64* ub = (const u64*)(out + (((long)sp * 32 + mh * 16) * 1024 + (long)dir * 512));
#pragma unroll
      for (int j = 0; j < 8; ++j) {
        const int idx = j * 256 + tid;           // 2048 u64 chunks
        const int r = idx >> 7, c4 = idx & 127;  // row, u64-within-row
        v8[j] = __hip_atomic_load((u64*)(ub + (long)r * 256 + c4),
                                  __ATOMIC_RELAXED, __HIP_MEMORY_SCOPE_AGENT);
      }
      while (true) {
        bool bad = false;
#pragma unroll
        for (int j = 0; j < 8; ++j) bad |= ((v8[j] & 0xffffULL) == 0xffffULL);
        if (!bad) break;
#pragma unroll
        for (int j = 0; j < 8; ++j) {
          if ((v8[j] & 0xffffULL) == 0xffffULL) {
            const int idx = j * 256 + tid;
            const int r = idx >> 7, c4 = idx & 127;
            v8[j] = __hip_atomic_load((u64*)(ub + (long)r * 256 + c4),
                                      __ATOMIC_RELAXED, __HIP_MEMORY_SCOPE_AGENT);
          }
        }
      }
    }
    // gate prefetch for t+1: issued here so the retry loop above never waits
    // on it; consumed one full step later.
    if (t < 127) {
      const int sn = dir ? (126 - t) : (t + 1);
      gnext = *(const u64*)(gbase + (long)sn * 65536);
    }
    if (t > 0) {
#pragma unroll
      for (int j = 0; j < 8; ++j) {
        const int idx = j * 256 + tid;
        const int r = idx >> 7, c4 = idx & 127;
        const int cc8 = c4 >> 1, hf = c4 & 1;
        *(u64*)&h_lds[r * 512 + ((cc8 ^ (r & 7)) << 3) + (hf << 2)] = v8[j];
      }
      __syncthreads();   // the ONLY barrier per step
      floatx4 acc1 = (floatx4){0.f, 0.f, 0.f, 0.f};
#pragma unroll
      for (int ks = 0; ks < 16; ks += 2) {   // 2 chains to halve dep latency
        const int slot0 = (ks * 4 + q) ^ (l15 & 7);
        bf16x8 a0 = *(const bf16x8*)&h_lds[l15 * 512 + slot0 * 8];
        acc = mfma16(a0, bfrag[ks], acc);
        const int slot1 = ((ks + 1) * 4 + q) ^ (l15 & 7);
        bf16x8 a1 = *(const bf16x8*)&h_lds[l15 * 512 + slot1 * 8];
        acc1 = mfma16(a1, bfrag[ks + 1], acc1);
      }
      acc += acc1;
    }
    // C-frag (row=batch=q*4+rg, col=n=l15) -> wave-local LDS transpose
#pragma unroll
    for (int rg = 0; rg < 4; ++rg)
      gsc[wv][q * 4 + rg][l15] = acc[rg] + bf2f((u32)((gcur >> (16 * rg)) & 0xffffu));
    // gsc[wv] is touched only by wave wv: wave-synchronous, no barrier
    const float gi = gsc[wv][l15][q];
    const float gf = gsc[wv][l15][4 + q];
    const float gg = gsc[wv][l15][8 + q];
    const float go = gsc[wv][l15][12 + q];
    const float iv = sigf(gi), fv = sigf(gf), gv = tanh_(gg), ov = sigf(go);
    c = fv * c + iv * gv;
    const float h = ov * tanh_(c);
    // pack 4 units (quads q=0..3, lanes 16 apart) -> one u64 store by q==0
    const u32 hv = (u32)f2bf(h);
    const u32 p1 = (u32)__shfl_xor((int)hv, 16);
    const u32 lo32 = hv | (p1 << 16);
    const u64 w64 = (u64)lo32 |
                    ((u64)(u32)__shfl_xor((int)lo32, 32) << 32);
    if (q == 0)
      __hip_atomic_store(
          (u64*)&out[((long)s * 32 + b_glob) * 1024 + dir * 512 + u0 + wv * 4],
          w64, __ATOMIC_RELAXED, __HIP_MEMORY_SCOPE_AGENT);
    gcur = gnext;
  }
}

// ---------------------------------------------------------------------------
// CRF: one block per (task, batch). Double-buffered alpha: 1 barrier/step.
// ---------------------------------------------------------------------------
template <int K>
static __device__ void crf_body(const float* __restrict__ feat, int off,
                                const int* __restrict__ labels, int b,
                                const float* __restrict__ start,
                                const float* __restrict__ end_,
                                const float* __restrict__ trans,
                                float* __restrict__ outp,
                                float* transT, float (*alpha)[64],
                                float* red)
{
  const int tid = threadIdx.x;
  for (int i = tid; i < K * K; i += 256) {
    int kk = i / K, kp2 = i % K;
    transT[kp2 * 65 + kk] = trans[i];
  }
  if (tid < K) alpha[0][tid] = start[tid] + feat[b * 96 + off + tid];
  __syncthreads();
  constexpr int Kq = K / 4;
  const int kp = tid >> 2, k4 = tid & 3;
  const bool act = kp < K;
  int p = 0;
  for (int s = 1; s < 128; ++s) {
    float x[Kq];
    float mx = -3e38f;
    if (act) {
      const float* tr = &transT[kp * 65 + k4 * Kq];
      const float* al = &alpha[p][k4 * Kq];
#pragma unroll
      for (int i2 = 0; i2 < Kq; ++i2) { x[i2] = al[i2] + tr[i2]; mx = fmaxf(mx, x[i2]); }
    }
    mx = fmaxf(mx, __shfl_xor(mx, 1));
    mx = fmaxf(mx, __shfl_xor(mx, 2));
    float ss = 0.f;
    if (act) {
#pragma unroll
      for (int i2 = 0; i2 < Kq; ++i2) ss += __expf(x[i2] - mx);
    }
    ss += __shfl_xor(ss, 1);
    ss += __shfl_xor(ss, 2);
    if (act && k4 == 0)
      alpha[p ^ 1][kp] = mx + __logf(ss) + feat[(s * 32 + b) * 96 + off + kp];
    __syncthreads();
    p ^= 1;
  }
  // numerator terms (one per time step)
  if (tid < 128) {
    const int tg = labels[tid * 32 + b];
    float term = feat[(tid * 32 + b) * 96 + off + tg];
    if (tid == 0) term += start[tg];
    else          term += trans[labels[(tid - 1) * 32 + b] * K + tg];
    if (tid == 127) term += end_[tg];
    red[tid] = term;
  }
  __syncthreads();
  if (tid == 0) {
    float num = 0.f;
    for (int i = 0; i < 128; ++i) num += red[i];
    float mx = -3e38f;
    for (int k = 0; k < K; ++k) mx = fmaxf(mx, alpha[p][k] + end_[k]);
    float ss = 0.f;
    for (int k = 0; k < K; ++k) ss += __expf(alpha[p][k] + end_[k] - mx);
    const float den = mx + __logf(ss);
    atomicAdd(outp, den - num);   // loss contribution = -(num - den)
  }
}

__global__ __launch_bounds__(256) void crf_kernel(
    const float* __restrict__ feat,
    const int* __restrict__ labp, const int* __restrict__ labm,
    const float* __restrict__ stp, const float* __restrict__ enp, const float* __restrict__ trp,
    const float* __restrict__ stm, const float* __restrict__ enm, const float* __restrict__ trm,
    float* __restrict__ outp)
{
  __shared__ float transT[64 * 65];
  __shared__ float alpha[2][64];
  __shared__ float red[128];
  const int task = blockIdx.x >> 5, b = blockIdx.x & 31;
  if (task == 0) crf_body<32>(feat, 0,  labp, b, stp, enp, trp, outp, transT, alpha, red);
  else           crf_body<64>(feat, 32, labm, b, stm, enm, trm, outp, transT, alpha, red);
}

// ---------------------------------------------------------------------------
// launch
// ---------------------------------------------------------------------------
extern "C" void kernel_launch(void* const* d_in, const int* in_sizes, int n_in,
                              void* d_out, int out_size, void* d_ws, size_t ws_size,
                              hipStream_t stream) {
  const float* src  = (const float*)d_in[0];
  const float* bert = (const float*)d_in[1];
  const int*   labp = (const int*)d_in[2];
  const int*   labm = (const int*)d_in[3];
  const float* w_ih = (const float*)d_in[4];
  const float* w_hh = (const float*)d_in[5];
  const float* b_ih = (const float*)d_in[6];
  const float* b_hh = (const float*)d_in[7];
  const float* hwp  = (const float*)d_in[8];
  const float* hbp  = (const float*)d_in[9];
  const float* hwm  = (const float*)d_in[10];
  const float* hbm  = (const float*)d_in[11];
  const float* stp  = (const float*)d_in[12];
  const float* enp  = (const float*)d_in[13];
  const float* trp  = (const float*)d_in[14];
  const float* stm  = (const float*)d_in[15];
  const float* enm  = (const float*)d_in[16];
  const float* trm  = (const float*)d_in[17];

  char* ws = (char*)d_ws;
  u16*   Wsrc     = (u16*)(ws + 0);          // 4096x256 bf16
  u16*   Wbert    = (u16*)(ws + 2097152);    // 4096x768 bf16
  u16*   Wih1     = (u16*)(ws + 8388608);    // 4096x1024 bf16
  u16*   Whh      = (u16*)(ws + 16777216);   // [2][2][2048][512] bf16
  u16*   SrcBf    = (u16*)(ws + 25165824);   // 4096x256 bf16
  u16*   BertBf   = (u16*)(ws + 27262976);   // 32x768 bf16
  u16*   Wheads   = (u16*)(ws + 27312128);   // 96x1024 bf16
  float* b0sum    = (float*)(ws + 27508736); // [4096]
  float* b1sum    = (float*)(ws + 27525120); // [4096]
  float* hb       = (float*)(ws + 27541504); // [96]
  float* bertpart = (float*)(ws + 27542272); // [32][4096]
  float* feat     = (float*)(ws + 28066560); // [4096][96]
  u16*   out0     = (u16*)(ws + 29639424);   // [128][32][1024] bf16
  u16*   out1     = (u16*)(ws + 38028032);   // [128][32][1024] bf16
  u16*   gates    = (u16*)(ws + 46416640);   // [2][128][2048][32] bf16 (33.5 MB)
  float* dout     = (float*)d_out;

  // sentinel fill: bf16 0xFFFF = NaN, unreachable for valid h in (-1,1)
  hipMemsetAsync(out0, 0xFF, 8388608, stream);
  hipMemsetAsync(out1, 0xFF, 8388608, stream);

  hipLaunchKernelGGL(prep_kernel, dim3(2048), dim3(256), 0, stream,
      w_ih, w_hh, b_ih, b_hh, src, bert, hwp, hbp, hwm, hbm,
      Wsrc, Wbert, Wih1, Whh, SrcBf, BertBf, Wheads, b0sum, b1sum, hb, dout);

  // bert part: [32,768]@[4096,768]^T + (b_ih0+b_hh0) -> bertpart[32][4096]
  hipLaunchKernelGGL(gemm_nt, dim3(32, 1), dim3(256), 0, stream,
      BertBf, 768, Wbert, 768, bertpart, 4096, 32, 4096, 768,
      b0sum, (const float*)nullptr, 0, 0);

  // layer0 input proj: src@Wsrc^T + bertpart -> bf16 gates (transposed)
  hipLaunchKernelGGL(gemm_nt, dim3(32, 32), dim3(256), 0, stream,
      SrcBf, 256, Wsrc, 256, (float*)gates, 0, 4096, 4096, 256,
      (const float*)nullptr, bertpart, 4096, 1);

  {
    const u16* g = gates; u16* o = out0; const u16* wh = Whh;
    void* args[] = {&g, &o, &wh};
    hipLaunchCooperativeKernel(reinterpret_cast<void*>(&lstm_rec),
                               dim3(128), dim3(256), args, 0, stream);
  }

  // layer1 input proj: out0@Wih1^T + b1sum -> bf16 gates (transposed)
  hipLaunchKernelGGL(gemm_nt, dim3(32, 32), dim3(256), 0, stream,
      out0, 1024, Wih1, 1024, (float*)gates, 0, 4096, 4096, 1024,
      b1sum, (const float*)nullptr, 0, 1);

  {
    const u16* g = gates; u16* o = out1; const u16* wh = Whh + 2L * 2048 * 512;
    void* args[] = {&g, &o, &wh};
    hipLaunchCooperativeKernel(reinterpret_cast<void*>(&lstm_rec),
                               dim3(128), dim3(256), args, 0, stream);
  }

  // heads: out1@[96,1024]^T + hb -> feat[4096][96]
  hipLaunchKernelGGL(gemm_nt, dim3(1, 32), dim3(256), 0, stream,
      out1, 1024, Wheads, 1024, feat, 96, 4096, 96, 1024,
      hb, (const float*)nullptr, 0, 0);

  hipLaunchKernelGGL(crf_kernel, dim3(64), dim3(256), 0, stream,
      feat, labp, labm, stp, enp, trp, stm, enm, trm, dout);
}

// Round 7
// 894.150 us; speedup vs baseline: 1.1494x; 1.1494x over previous
//
#include <hip/hip_runtime.h>

// ---------------------------------------------------------------------------
// BiLSTM-CRF forward loss on MI355X (gfx950).
// memset(out=NaN) + prep -> bert GEMM -> layer0 input-proj GEMM (bf16 gates)
//   -> coop LSTM (layer0) -> layer1 input-proj GEMM -> coop LSTM (layer1)
//   -> heads GEMM -> CRF.
// Round 7: wave-ordered gate layout — G[dir][s][mh][ub][wv][l15*4+q] u64
// entries (4 batches packed). An lstm wave reads its 64 gate u64s as 512 B
// CONTIGUOUS (R6's 64B-stride scatter was the regression). Gate prefetch
// back at R5 position (before staging loads).
// ---------------------------------------------------------------------------

typedef unsigned short u16;
typedef unsigned int u32;
typedef unsigned long long u64;
typedef __attribute__((ext_vector_type(8))) __bf16 bf16x8;
typedef __attribute__((ext_vector_type(4))) float floatx4;

static __device__ __forceinline__ u16 f2bf(float f) {
  u32 u = __float_as_uint(f);
  u += 0x7fffu + ((u >> 16) & 1u);   // round-to-nearest-even
  return (u16)(u >> 16);
}
static __device__ __forceinline__ float bf2f(u32 bits) {
  return __uint_as_float(bits << 16);
}
static __device__ __forceinline__ float sigf(float x) {
  return 1.0f / (1.0f + __expf(-x));
}
static __device__ __forceinline__ float tanh_(float x) {
  return 1.0f - 2.0f / (1.0f + __expf(2.0f * x));
}
static __device__ __forceinline__ floatx4 mfma16(bf16x8 a, bf16x8 b, floatx4 c) {
  return __builtin_amdgcn_mfma_f32_16x16x32_bf16(a, b, c, 0, 0, 0);
}

// ---------------------------------------------------------------------------
// prep: fp32->bf16 conversions + bias sums + zero d_out
// ---------------------------------------------------------------------------
__global__ __launch_bounds__(256) void prep_kernel(
    const float* __restrict__ w_ih, const float* __restrict__ w_hh,
    const float* __restrict__ b_ih, const float* __restrict__ b_hh,
    const float* __restrict__ src,  const float* __restrict__ bert,
    const float* __restrict__ hwp,  const float* __restrict__ hbp,
    const float* __restrict__ hwm,  const float* __restrict__ hbm,
    u16* __restrict__ Wsrc, u16* __restrict__ Wbert, u16* __restrict__ Wih1,
    u16* __restrict__ Whh,  u16* __restrict__ SrcBf, u16* __restrict__ BertBf,
    u16* __restrict__ Wheads, float* __restrict__ b0sum, float* __restrict__ b1sum,
    float* __restrict__ hb, float* __restrict__ dout)
{
  const int NA = 4194304;  // w_ih layer0 -> Wsrc (cols 0:256) + Wbert (256:1024)
  const int NB = 4194304;  // w_ih layer1
  const int NC = 4194304;  // w_hh (both layers)
  const int ND = 1048576;  // src
  const int NE = 24576;    // bert
  const int NF = 98304;    // head weights
  const int NG = 8192;     // bias sums
  const int NH = 96;       // head bias
  const int TOTAL = NA + NB + NC + ND + NE + NF + NG + NH + 1;
  for (int i = blockIdx.x * 256 + threadIdx.x; i < TOTAL; i += gridDim.x * 256) {
    int x = i;
    if (x < NA) {
      int c = x & 1023, r = x >> 10;          // r = dir*2048 + row
      float v = w_ih[x];
      if (c < 256) Wsrc[r * 256 + c] = f2bf(v);
      else         Wbert[r * 768 + (c - 256)] = f2bf(v);
      continue;
    }
    x -= NA;
    if (x < NB) { Wih1[x] = f2bf(w_ih[NA + x]); continue; }
    x -= NB;
    if (x < NC) { Whh[x] = f2bf(w_hh[x]); continue; }
    x -= NC;
    if (x < ND) { SrcBf[x] = f2bf(src[x]); continue; }
    x -= ND;
    if (x < NE) { BertBf[x] = f2bf(bert[x]); continue; }
    x -= NE;
    if (x < NF) {
      Wheads[x] = f2bf(x < 32768 ? hwp[x] : hwm[x - 32768]);
      continue;
    }
    x -= NF;
    if (x < NG) {
      float v = b_ih[x] + b_hh[x];
      if (x < 4096) b0sum[x] = v; else b1sum[x - 4096] = v;
      continue;
    }
    x -= NG;
    if (x < NH) { hb[x] = (x < 32) ? hbp[x] : hbm[x - 32]; continue; }
    dout[0] = 0.f;
  }
}

// ---------------------------------------------------------------------------
// bf16 NT GEMM: acc[m][n] = sum_k A[m][k]*B[n][k] (+bias[n]) (+aux[m%32][n])
// 128x128 tile, BK=64, XOR-swizzled LDS.
// mode 0: C fp32 at C[m*ldc+n].
// mode 1: bf16 gates, wave-ordered for lstm_rec: u64 entry (4 batches) at
//   [((((dir*128+s)*2+mh)*32+ub)*4+wv)*64 + l15*4 + q]
//   where n=dir*2048+nn, gt=nn>>9, u=nn&511, ub=u>>4, wv=(u&15)>>2,
//   l15=gt*4+(u&3); m=s*32+b, mh=b>>4, q=(b>>2)&3, rg packs b&3.
// ---------------------------------------------------------------------------
__global__ __launch_bounds__(256) void gemm_nt(
    const u16* __restrict__ A, int lda,
    const u16* __restrict__ B, int ldb,
    float* __restrict__ C, int ldc,
    int M, int N, int K,
    const float* __restrict__ bias_n,
    const float* __restrict__ auxBN, int auxld,
    int mode)
{
  __shared__ __align__(16) u16 As[128 * 64];
  __shared__ __align__(16) u16 Bs[128 * 64];
  const int m0 = blockIdx.y * 128, n0 = blockIdx.x * 128;
  const int tid = threadIdx.x;
  const int wv = tid >> 6, ln = tid & 63;
  const int wm = wv & 1, wn = wv >> 1;
  const int q = ln >> 4, l15 = ln & 15;
  floatx4 acc[4][4];
#pragma unroll
  for (int a = 0; a < 4; ++a)
#pragma unroll
    for (int b2 = 0; b2 < 4; ++b2) acc[a][b2] = (floatx4){0.f, 0.f, 0.f, 0.f};

  for (int kk = 0; kk < K; kk += 64) {
    __syncthreads();
#pragma unroll
    for (int j = 0; j < 4; ++j) {
      const int idx = j * 256 + tid;   // 1024 16B chunks per operand tile
      const int r = idx >> 3, cc = idx & 7;
      const int slot = cc ^ (r & 7);
      const int ra = min(m0 + r, M - 1);
      *(int4*)&As[r * 64 + slot * 8] = *(const int4*)&A[(long)ra * lda + kk + cc * 8];
      const int rb = min(n0 + r, N - 1);
      *(int4*)&Bs[r * 64 + slot * 8] = *(const int4*)&B[(long)rb * ldb + kk + cc * 8];
    }
    __syncthreads();
#pragma unroll
    for (int ks = 0; ks < 2; ++ks) {
      bf16x8 af[4], bf[4];
#pragma unroll
      for (int im = 0; im < 4; ++im) {
        const int r = wm * 64 + im * 16 + l15;
        const int slot = (ks * 4 + q) ^ (r & 7);
        af[im] = *(const bf16x8*)&As[r * 64 + slot * 8];
      }
#pragma unroll
      for (int jn = 0; jn < 4; ++jn) {
        const int r = wn * 64 + jn * 16 + l15;
        const int slot = (ks * 4 + q) ^ (r & 7);
        bf[jn] = *(const bf16x8*)&Bs[r * 64 + slot * 8];
      }
#pragma unroll
      for (int im = 0; im < 4; ++im)
#pragma unroll
        for (int jn = 0; jn < 4; ++jn)
          acc[im][jn] = mfma16(af[im], bf[jn], acc[im][jn]);
    }
  }
  // epilogue: C/D layout col=lane&15, row=(lane>>4)*4+reg
  if (mode == 0) {
#pragma unroll
    for (int im = 0; im < 4; ++im)
#pragma unroll
      for (int jn = 0; jn < 4; ++jn) {
        const int n = n0 + wn * 64 + jn * 16 + l15;
        if (n < N) {
          const float badd = bias_n ? bias_n[n] : 0.f;
#pragma unroll
          for (int rg = 0; rg < 4; ++rg) {
            const int m = m0 + wm * 64 + im * 16 + q * 4 + rg;
            if (m < M) {
              float v = acc[im][jn][rg] + badd;
              if (auxBN) v += auxBN[(long)(m & 31) * auxld + n];
              C[(long)m * ldc + n] = v;
            }
          }
        }
      }
  } else {
    u64* G = (u64*)C;
#pragma unroll
    for (int im = 0; im < 4; ++im)
#pragma unroll
      for (int jn = 0; jn < 4; ++jn) {
        const int n = n0 + wn * 64 + jn * 16 + l15;
        const int dirsel = n >> 11, nn = n & 2047;
        const int gt = nn >> 9, u = nn & 511;
        const int ub = u >> 4, low = u & 15;
        const int wvl = low >> 2, jl = low & 3;
        const int l15l = gt * 4 + jl;
        const int m = m0 + wm * 64 + im * 16 + q * 4;   // rg=0 row
        const int s = m >> 5, b0 = m & 31;
        const int mh = b0 >> 4, qq = (b0 >> 2) & 3;
        const float badd = bias_n ? bias_n[n] : 0.f;
        u64 pk = 0;
#pragma unroll
        for (int rg = 0; rg < 4; ++rg) {
          float v = acc[im][jn][rg] + badd;
          if (auxBN) v += auxBN[(long)(b0 + rg) * auxld + n];
          pk |= (u64)f2bf(v) << (16 * rg);
        }
        G[(((((long)dirsel * 128 + s) * 2 + mh) * 32 + ub) * 4 + wvl) * 64
          + l15l * 4 + qq] = pk;
      }
  }
}

// ---------------------------------------------------------------------------
// persistent cooperative LSTM recurrence, one layer, both directions.
// 128 blocks x 256 thr: block = (dir, batch-half of 16, 16 hidden units).
// Dataflow sync: out pre-filled with bf16 NaN 0xFFFF; producers store h as
// atomic u64; consumers retry coalesced atomic u64 loads until non-sentinel.
// Gates: wave-ordered bf16 layout, one contiguous 512 B load per wave/step.
// ---------------------------------------------------------------------------
__global__ __launch_bounds__(256, 1) void lstm_rec(
    const u16* __restrict__ gates,  // wave-ordered, see gemm_nt mode 1
    u16* __restrict__ out,          // [128][32][1024] bf16 (fwd | bwd)
    const u16* __restrict__ whh)    // [2][2048][512] bf16 (this layer)
{
  __shared__ __align__(16) u16 h_lds[16 * 512];
  __shared__ float gsc[4][16][17];
  const int bid = blockIdx.x;
  const int dir = bid >> 6;
  const int mh = (bid >> 5) & 1;
  const int ub = bid & 31;
  const int u0 = ub * 16;
  const int tid = threadIdx.x;
  const int wv = tid >> 6;
  const int ln = tid & 63;
  const int q = ln >> 4, l15 = ln & 15;

  // gate row for this lane's B-frag column n=l15: (n>>2)=gate type, (n&3)=unit
  const int gate_r = (l15 >> 2) * 512 + u0 + wv * 4 + (l15 & 3);

  bf16x8 bfrag[16];
  {
    const u16* wp = whh + ((long)dir * 2048 + gate_r) * 512 + q * 8;
#pragma unroll
    for (int ks = 0; ks < 16; ++ks)
      bfrag[ks] = *(const bf16x8*)(wp + ks * 32);
  }

  float c = 0.f;                       // cell state for (b_glob, j_lane)
  const int b_glob = mh * 16 + l15;    // batch (update phase)

  // wave-ordered gate pointer: stride per s = 2*32*4*64 = 16384 u64
  const u64* gbase = (const u64*)gates
      + ((((long)dir * 128 * 2 + mh) * 32 + ub) * 4 + wv) * 64 + l15 * 4 + q;

  u64 gcur = gbase[(long)(dir ? 127 : 0) * 16384];
  u64 gnext = 0;

  for (int t = 0; t < 128; ++t) {
    const int s = dir ? (127 - t) : t;
    // gate prefetch for t+1: coalesced 512 B per wave, issued before staging
    // so it completes alongside the staging loads; consumed next step.
    if (t < 127) {
      const int sn = dir ? (126 - t) : (t + 1);
      gnext = gbase[(long)sn * 16384];
    }
    floatx4 acc = (floatx4){0.f, 0.f, 0.f, 0.f};
    if (t > 0) {
      // stage h(t-1): 16 rows x 512 cols bf16. Coalesced device-scope u64
      // loads; each u64 = one producer wave's atomic store -> check low u16.
      const int sp = dir ? (s + 1) : (s - 1);
      const u64* ubp = (const u64*)(out + (((long)sp * 32 + mh * 16) * 1024 + (long)dir * 512));
      u64 v8[8];
#pragma unroll
      for (int j = 0; j < 8; ++j) {
        const int idx = j * 256 + tid;           // 2048 u64 chunks
        const int r = idx >> 7, c4 = idx & 127;  // row, u64-within-row
        v8[j] = __hip_atomic_load((u64*)(ubp + (long)r * 256 + c4),
                                  __ATOMIC_RELAXED, __HIP_MEMORY_SCOPE_AGENT);
      }
      while (true) {
        bool bad = false;
#pragma unroll
        for (int j = 0; j < 8; ++j) bad |= ((v8[j] & 0xffffULL) == 0xffffULL);
        if (!bad) break;
#pragma unroll
        for (int j = 0; j < 8; ++j) {
          if ((v8[j] & 0xffffULL) == 0xffffULL) {
            const int idx = j * 256 + tid;
            const int r = idx >> 7, c4 = idx & 127;
            v8[j] = __hip_atomic_load((u64*)(ubp + (long)r * 256 + c4),
                                      __ATOMIC_RELAXED, __HIP_MEMORY_SCOPE_AGENT);
          }
        }
      }
#pragma unroll
      for (int j = 0; j < 8; ++j) {
        const int idx = j * 256 + tid;
        const int r = idx >> 7, c4 = idx & 127;
        const int cc8 = c4 >> 1, hf = c4 & 1;
        *(u64*)&h_lds[r * 512 + ((cc8 ^ (r & 7)) << 3) + (hf << 2)] = v8[j];
      }
      __syncthreads();   // the ONLY barrier per step
      floatx4 acc1 = (floatx4){0.f, 0.f, 0.f, 0.f};
#pragma unroll
      for (int ks = 0; ks < 16; ks += 2) {   // 2 chains to halve dep latency
        const int slot0 = (ks * 4 + q) ^ (l15 & 7);
        bf16x8 a0 = *(const bf16x8*)&h_lds[l15 * 512 + slot0 * 8];
        acc = mfma16(a0, bfrag[ks], acc);
        const int slot1 = ((ks + 1) * 4 + q) ^ (l15 & 7);
        bf16x8 a1 = *(const bf16x8*)&h_lds[l15 * 512 + slot1 * 8];
        acc1 = mfma16(a1, bfrag[ks + 1], acc1);
      }
      acc += acc1;
    }
    // C-frag (row=batch=q*4+rg, col=n=l15) -> wave-local LDS transpose
#pragma unroll
    for (int rg = 0; rg < 4; ++rg)
      gsc[wv][q * 4 + rg][l15] = acc[rg] + bf2f((u32)((gcur >> (16 * rg)) & 0xffffu));
    // gsc[wv] is touched only by wave wv: wave-synchronous, no barrier
    const float gi = gsc[wv][l15][q];
    const float gf = gsc[wv][l15][4 + q];
    const float gg = gsc[wv][l15][8 + q];
    const float go = gsc[wv][l15][12 + q];
    const float iv = sigf(gi), fv = sigf(gf), gv = tanh_(gg), ov = sigf(go);
    c = fv * c + iv * gv;
    const float h = ov * tanh_(c);
    // pack 4 units (quads q=0..3, lanes 16 apart) -> one u64 store by q==0
    const u32 hv = (u32)f2bf(h);
    const u32 p1 = (u32)__shfl_xor((int)hv, 16);
    const u32 lo32 = hv | (p1 << 16);
    const u64 w64 = (u64)lo32 |
                    ((u64)(u32)__shfl_xor((int)lo32, 32) << 32);
    if (q == 0)
      __hip_atomic_store(
          (u64*)&out[((long)s * 32 + b_glob) * 1024 + dir * 512 + u0 + wv * 4],
          w64, __ATOMIC_RELAXED, __HIP_MEMORY_SCOPE_AGENT);
    gcur = gnext;
  }
}

// ---------------------------------------------------------------------------
// CRF: one block per (task, batch). Double-buffered alpha: 1 barrier/step.
// ---------------------------------------------------------------------------
template <int K>
static __device__ void crf_body(const float* __restrict__ feat, int off,
                                const int* __restrict__ labels, int b,
                                const float* __restrict__ start,
                                const float* __restrict__ end_,
                                const float* __restrict__ trans,
                                float* __restrict__ outp,
                                float* transT, float (*alpha)[64],
                                float* red)
{
  const int tid = threadIdx.x;
  for (int i = tid; i < K * K; i += 256) {
    int kk = i / K, kp2 = i % K;
    transT[kp2 * 65 + kk] = trans[i];
  }
  if (tid < K) alpha[0][tid] = start[tid] + feat[b * 96 + off + tid];
  __syncthreads();
  constexpr int Kq = K / 4;
  const int kp = tid >> 2, k4 = tid & 3;
  const bool act = kp < K;
  int p = 0;
  for (int s = 1; s < 128; ++s) {
    float x[Kq];
    float mx = -3e38f;
    if (act) {
      const float* tr = &transT[kp * 65 + k4 * Kq];
      const float* al = &alpha[p][k4 * Kq];
#pragma unroll
      for (int i2 = 0; i2 < Kq; ++i2) { x[i2] = al[i2] + tr[i2]; mx = fmaxf(mx, x[i2]); }
    }
    mx = fmaxf(mx, __shfl_xor(mx, 1));
    mx = fmaxf(mx, __shfl_xor(mx, 2));
    float ss = 0.f;
    if (act) {
#pragma unroll
      for (int i2 = 0; i2 < Kq; ++i2) ss += __expf(x[i2] - mx);
    }
    ss += __shfl_xor(ss, 1);
    ss += __shfl_xor(ss, 2);
    if (act && k4 == 0)
      alpha[p ^ 1][kp] = mx + __logf(ss) + feat[(s * 32 + b) * 96 + off + kp];
    __syncthreads();
    p ^= 1;
  }
  // numerator terms (one per time step)
  if (tid < 128) {
    const int tg = labels[tid * 32 + b];
    float term = feat[(tid * 32 + b) * 96 + off + tg];
    if (tid == 0) term += start[tg];
    else          term += trans[labels[(tid - 1) * 32 + b] * K + tg];
    if (tid == 127) term += end_[tg];
    red[tid] = term;
  }
  __syncthreads();
  if (tid == 0) {
    float num = 0.f;
    for (int i = 0; i < 128; ++i) num += red[i];
    float mx = -3e38f;
    for (int k = 0; k < K; ++k) mx = fmaxf(mx, alpha[p][k] + end_[k]);
    float ss = 0.f;
    for (int k = 0; k < K; ++k) ss += __expf(alpha[p][k] + end_[k] - mx);
    const float den = mx + __logf(ss);
    atomicAdd(outp, den - num);   // loss contribution = -(num - den)
  }
}

__global__ __launch_bounds__(256) void crf_kernel(
    const float* __restrict__ feat,
    const int* __restrict__ labp, const int* __restrict__ labm,
    const float* __restrict__ stp, const float* __restrict__ enp, const float* __restrict__ trp,
    const float* __restrict__ stm, const float* __restrict__ enm, const float* __restrict__ trm,
    float* __restrict__ outp)
{
  __shared__ float transT[64 * 65];
  __shared__ float alpha[2][64];
  __shared__ float red[128];
  const int task = blockIdx.x >> 5, b = blockIdx.x & 31;
  if (task == 0) crf_body<32>(feat, 0,  labp, b, stp, enp, trp, outp, transT, alpha, red);
  else           crf_body<64>(feat, 32, labm, b, stm, enm, trm, outp, transT, alpha, red);
}

// ---------------------------------------------------------------------------
// launch
// ---------------------------------------------------------------------------
extern "C" void kernel_launch(void* const* d_in, const int* in_sizes, int n_in,
                              void* d_out, int out_size, void* d_ws, size_t ws_size,
                              hipStream_t stream) {
  const float* src  = (const float*)d_in[0];
  const float* bert = (const float*)d_in[1];
  const int*   labp = (const int*)d_in[2];
  const int*   labm = (const int*)d_in[3];
  const float* w_ih = (const float*)d_in[4];
  const float* w_hh = (const float*)d_in[5];
  const float* b_ih = (const float*)d_in[6];
  const float* b_hh = (const float*)d_in[7];
  const float* hwp  = (const float*)d_in[8];
  const float* hbp  = (const float*)d_in[9];
  const float* hwm  = (const float*)d_in[10];
  const float* hbm  = (const float*)d_in[11];
  const float* stp  = (const float*)d_in[12];
  const float* enp  = (const float*)d_in[13];
  const float* trp  = (const float*)d_in[14];
  const float* stm  = (const float*)d_in[15];
  const float* enm  = (const float*)d_in[16];
  const float* trm  = (const float*)d_in[17];

  char* ws = (char*)d_ws;
  u16*   Wsrc     = (u16*)(ws + 0);          // 4096x256 bf16
  u16*   Wbert    = (u16*)(ws + 2097152);    // 4096x768 bf16
  u16*   Wih1     = (u16*)(ws + 8388608);    // 4096x1024 bf16
  u16*   Whh      = (u16*)(ws + 16777216);   // [2][2][2048][512] bf16
  u16*   SrcBf    = (u16*)(ws + 25165824);   // 4096x256 bf16
  u16*   BertBf   = (u16*)(ws + 27262976);   // 32x768 bf16
  u16*   Wheads   = (u16*)(ws + 27312128);   // 96x1024 bf16
  float* b0sum    = (float*)(ws + 27508736); // [4096]
  float* b1sum    = (float*)(ws + 27525120); // [4096]
  float* hb       = (float*)(ws + 27541504); // [96]
  float* bertpart = (float*)(ws + 27542272); // [32][4096]
  float* feat     = (float*)(ws + 28066560); // [4096][96]
  u16*   out0     = (u16*)(ws + 29639424);   // [128][32][1024] bf16
  u16*   out1     = (u16*)(ws + 38028032);   // [128][32][1024] bf16
  u16*   gates    = (u16*)(ws + 46416640);   // wave-ordered bf16 (33.5 MB)
  float* dout     = (float*)d_out;

  // sentinel fill: bf16 0xFFFF = NaN, unreachable for valid h in (-1,1)
  hipMemsetAsync(out0, 0xFF, 8388608, stream);
  hipMemsetAsync(out1, 0xFF, 8388608, stream);

  hipLaunchKernelGGL(prep_kernel, dim3(2048), dim3(256), 0, stream,
      w_ih, w_hh, b_ih, b_hh, src, bert, hwp, hbp, hwm, hbm,
      Wsrc, Wbert, Wih1, Whh, SrcBf, BertBf, Wheads, b0sum, b1sum, hb, dout);

  // bert part: [32,768]@[4096,768]^T + (b_ih0+b_hh0) -> bertpart[32][4096]
  hipLaunchKernelGGL(gemm_nt, dim3(32, 1), dim3(256), 0, stream,
      BertBf, 768, Wbert, 768, bertpart, 4096, 32, 4096, 768,
      b0sum, (const float*)nullptr, 0, 0);

  // layer0 input proj: src@Wsrc^T + bertpart -> bf16 gates (wave-ordered)
  hipLaunchKernelGGL(gemm_nt, dim3(32, 32), dim3(256), 0, stream,
      SrcBf, 256, Wsrc, 256, (float*)gates, 0, 4096, 4096, 256,
      (const float*)nullptr, bertpart, 4096, 1);

  {
    const u16* g = gates; u16* o = out0; const u16* wh = Whh;
    void* args[] = {&g, &o, &wh};
    hipLaunchCooperativeKernel(reinterpret_cast<void*>(&lstm_rec),
                               dim3(128), dim3(256), args, 0, stream);
  }

  // layer1 input proj: out0@Wih1^T + b1sum -> bf16 gates (wave-ordered)
  hipLaunchKernelGGL(gemm_nt, dim3(32, 32), dim3(256), 0, stream,
      out0, 1024, Wih1, 1024, (float*)gates, 0, 4096, 4096, 1024,
      b1sum, (const float*)nullptr, 0, 1);

  {
    const u16* g = gates; u16* o = out1; const u16* wh = Whh + 2L * 2048 * 512;
    void* args[] = {&g, &o, &wh};
    hipLaunchCooperativeKernel(reinterpret_cast<void*>(&lstm_rec),
                               dim3(128), dim3(256), args, 0, stream);
  }

  // heads: out1@[96,1024]^T + hb -> feat[4096][96]
  hipLaunchKernelGGL(gemm_nt, dim3(1, 32), dim3(256), 0, stream,
      out1, 1024, Wheads, 1024, feat, 96, 4096, 96, 1024,
      hb, (const float*)nullptr, 0, 0);

  hipLaunchKernelGGL(crf_kernel, dim3(64), dim3(256), 0, stream,
      feat, labp, labm, stp, enp, trp, stm, enm, trm, dout);
}